// Round 6
// baseline (4358.886 us; speedup 1.0000x reference)
//
#include <hip/hip_runtime.h>
#include <math.h>

#define Bsz 128
#define Tsz 512
#define Hsz 1024
#define NM  8
#define MS  128
#define NT  512
#define NPAIR 36

// ---------------------------------------------------------------------------
// Retile W_hh into block-major WB.
//   pair p = tri index of (r,c), r<=c: p = c(c+1)/2 + r.
//   p==0 : WB[0][row*128 + j]  (j-fastest: feeds per-row register cache)
//   p>=1 : WB[p][j*128 + row]  (row-fastest: lane-coalesced float4-of-rows)
// ---------------------------------------------------------------------------
__global__ __launch_bounds__(256)
void retile_whh(const float* __restrict__ W, float* __restrict__ WB) {
    __shared__ float tile[MS][MS + 1];
    const int p = blockIdx.x;
    int c = 0;
    while ((c + 1) * (c + 2) / 2 <= p) ++c;
    const int r = p - c * (c + 1) / 2;
    const int t = threadIdx.x;
    if (p == 0) {
        for (int idx = t; idx < MS * MS; idx += 256) {
            const int row = idx >> 7, j = idx & (MS - 1);
            WB[idx] = W[row * Hsz + j];
        }
        return;
    }
    for (int idx = t; idx < MS * MS; idx += 256) {
        const int row = idx >> 7, j = idx & (MS - 1);
        tile[row][j] = W[(size_t)(r * MS + row) * Hsz + c * MS + j];
    }
    __syncthreads();
    float* wb = WB + (size_t)p * MS * MS;
    for (int idx = t; idx < MS * MS; idx += 256) {
        const int j = idx >> 7, row = idx & (MS - 1);
        wb[idx] = tile[row][j];
    }
}

__device__ __forceinline__ float fast_tanh(float x) {
    const float e = __expf(2.0f * x);
    return 1.0f - 2.0f * __builtin_amdgcn_rcpf(e + 1.0f);
}

// ---------------------------------------------------------------------------
// Persistent per-batch-element Clockwork RNN. grid=128, block=512 (8 waves).
// Exactly 2 __syncthreads per step.
//
// Sp1[p][row]: ONE value per (pair,row) (quad-shfl reduced in refresh).
// P1: row g=tid (+512); reads (8-r) Sp1 scalars, tanh, writes h; fused
//     quad-reduced fc partials into WPq[t&1][g>>6][(g>>2)&15].
// refresh00: all 512 threads, W00 in registers (row=tid>>2, jc=tid&3,
//     chunk rotation per jc for bank-free h reads), 2-level shfl_xor.
// refresh_hi: 4 pairs concurrent (slot=tid>>7); thread owns 4 rows x 32 j
//     (rotated), quad shfl_xor over hjq, float4 write to Sp1.
// Pair scheduling: even t -> row-0 pairs (0,c), c<=A (critical for t+1);
//     odd t -> deferred pairs (r>=1, c<=A(t-1)) using unchanged h_c.
// thread0 folds per-module output sums AFTER barrier2 (overlaps next P1;
//     WPq parity double-buffer protects the WAR).
// ---------------------------------------------------------------------------
__global__ __launch_bounds__(NT, 2)
void cwrnn_kernel(const float* __restrict__ x,      // [B, T+1, 2, 1]
                  const float* __restrict__ W_ih,   // [H, 2]
                  const float* __restrict__ fc_w,   // [2, H]
                  const float* __restrict__ fc_b,   // [2]
                  const float* __restrict__ enc_w,  // [H, 2]
                  const float* __restrict__ WB,     // retiled W_hh blocks
                  float* __restrict__ out)          // [B, T, 2]
{
    __shared__ float  h_s[Hsz];
    __shared__ float  Sp1[NPAIR][MS];     // 18 KB
    __shared__ float2 x_s[Tsz + 1];
    __shared__ float2 wih_s[Hsz];
    __shared__ float2 fcw_s[Hsz];
    __shared__ float  out_s[Tsz * 2];
    __shared__ float2 WPq[2][16][16];     // [parity][virtual wave][quad]

    const int tid  = threadIdx.x;
    const int b    = blockIdx.x;

    const float2* xb = (const float2*)(x + (size_t)b * (Tsz + 1) * 2);

    for (int i = tid; i < Tsz + 1; i += NT) x_s[i] = xb[i];
    for (int i = tid; i < Hsz; i += NT) wih_s[i] = ((const float2*)W_ih)[i];
    for (int i = tid; i < Hsz; i += NT)
        fcw_s[i] = make_float2(fc_w[i], fc_w[Hsz + i]);
    const float fb0 = fc_b[0], fb1 = fc_b[1];

    // ---- (0,0) register cache: row=tid>>2, jc=tid&3, rotated chunk order --
    const int row00 = tid >> 2;           // 0..127
    const int jc    = tid & 3;
    float4 w00[8];
    #pragma unroll
    for (int u = 0; u < 8; ++u) {
        const int uu = (u + 2 * jc) & 7;
        w00[u] = *(const float4*)(WB + row00 * MS + jc * 32 + uu * 4);
    }

    // ---- refresh_hi mapping ----
    const int slot = tid >> 7;            // 0..3 pair slot
    const int hs   = tid & 127;
    const int hrow = (hs >> 2) << 2;      // 0,4,...,124
    const int hjq  = hs & 3;

    // ---- h0 = x[:,0] @ enc_w.T ----
    {
        const float2 x0 = xb[0];
        for (int i = tid; i < Hsz; i += NT) {
            const float2 ew = ((const float2*)enc_w)[i];
            h_s[i] = x0.x * ew.x + x0.y * ew.y;
        }
    }
    __syncthreads();

    auto refresh00 = [&]() {
        float a = 0.f;
        #pragma unroll
        for (int u = 0; u < 8; ++u) {
            const int uu = (u + 2 * jc) & 7;
            const float4 hv = *(const float4*)(h_s + jc * 32 + uu * 4);
            a += w00[u].x * hv.x + w00[u].y * hv.y + w00[u].z * hv.z + w00[u].w * hv.w;
        }
        a += __shfl_xor(a, 1, 64);
        a += __shfl_xor(a, 2, 64);
        if (jc == 0) Sp1[0][row00] = a;
    };

    auto do_pair = [&](int p, int c) {
        const float* wbp = WB + (size_t)p * MS * MS + hrow;
        const float* hc  = h_s + c * MS;
        float4 acc = {0.f, 0.f, 0.f, 0.f};
        #pragma unroll 8
        for (int jj = 0; jj < 32; ++jj) {
            const int j = hjq * 32 + ((jj + hjq * 8) & 31);   // rotated banks
            const float hj = hc[j];
            const float4 wv = *(const float4*)(wbp + j * MS);
            acc.x += wv.x * hj; acc.y += wv.y * hj;
            acc.z += wv.z * hj; acc.w += wv.w * hj;
        }
        acc.x += __shfl_xor(acc.x, 1, 64); acc.y += __shfl_xor(acc.y, 1, 64);
        acc.z += __shfl_xor(acc.z, 1, 64); acc.w += __shfl_xor(acc.w, 1, 64);
        acc.x += __shfl_xor(acc.x, 2, 64); acc.y += __shfl_xor(acc.y, 2, 64);
        acc.z += __shfl_xor(acc.z, 2, 64); acc.w += __shfl_xor(acc.w, 2, 64);
        if (hjq == 0) *(float4*)&Sp1[p][hrow] = acc;
    };

    // mode 0: pairs (0,c) c=1..A | mode 1: pairs (1<=r<=c<=A) | mode 2: all
    auto refresh_hi = [&](int mode, int A) {
        int n = 0;
        for (int c = 1; c <= A; ++c) {
            const int base = c * (c + 1) / 2;
            const int rlo = (mode == 1) ? 1 : 0;
            const int rhi = (mode == 0) ? 0 : c;
            for (int r = rlo; r <= rhi; ++r) {
                if ((n++ & 3) == slot) do_pair(base + r, c);
            }
        }
    };

    refresh00();
    refresh_hi(2, 7);                     // all 36 pairs from h0
    __syncthreads();

    // thread0's cached per-module output sums
    float o0r[NM] = {0,0,0,0,0,0,0,0};
    float o1r[NM] = {0,0,0,0,0,0,0,0};
    float Sall0 = 0.f, Sall1 = 0.f;

    for (int t = 0; t < Tsz; ++t) {
        const int A = (t == 0) ? 7 : min(__ffs(t) - 1, 7);
        const int nrows = (A + 1) * MS;
        const float2 xt = x_s[t + 1];
        const int par = t & 1;

        // ---- P1: h update + fused quad-reduced fc partials ----
        for (int g = tid; g < nrows; g += NT) {
            const int r  = g >> 7;
            const int il = g & (MS - 1);
            const float2 wih2 = wih_s[g];
            float pre = xt.x * wih2.x + xt.y * wih2.y;
            for (int c = r; c < NM; ++c)
                pre += Sp1[c * (c + 1) / 2 + r][il];
            const float h = fast_tanh(pre);
            h_s[g] = h;
            const float2 fw = fcw_s[g];
            float p0 = h * fw.x, p1 = h * fw.y;
            p0 += __shfl_xor(p0, 1, 64); p1 += __shfl_xor(p1, 1, 64);
            p0 += __shfl_xor(p0, 2, 64); p1 += __shfl_xor(p1, 2, 64);
            if ((g & 3) == 0) WPq[par][g >> 6][(g >> 2) & 15] = make_float2(p0, p1);
        }
        __syncthreads();                  // barrier 1

        // ---- refresh phase ----
        refresh00();                      // (0,0) from current h, every step
        if ((t & 1) == 0) {
            refresh_hi(0, A);             // row-0 pairs: needed at t+1
        } else {
            const int Aprev = (t == 1) ? 7 : min(__ffs(t - 1) - 1, 7);
            refresh_hi(1, Aprev);         // deferred r>=1 pairs (h_c unchanged)
        }
        __syncthreads();                  // barrier 2

        // ---- thread0: fold per-module sums, emit out[t] (overlaps next P1) --
        if (tid == 0) {
            #pragma unroll
            for (int m = 0; m < NM; ++m) {
                if (m <= A) {
                    float n0 = 0.f, n1 = 0.f;
                    #pragma unroll
                    for (int q = 0; q < 16; ++q) {
                        const float2 a = WPq[par][2 * m][q];
                        const float2 c2 = WPq[par][2 * m + 1][q];
                        n0 += a.x + c2.x; n1 += a.y + c2.y;
                    }
                    Sall0 += n0 - o0r[m]; Sall1 += n1 - o1r[m];
                    o0r[m] = n0; o1r[m] = n1;
                }
            }
            out_s[2 * t]     = Sall0 + fb0;
            out_s[2 * t + 1] = Sall1 + fb1;
        }
        // WPq WAR: next write to WPq[par] is at P1 of t+2, which thread0
        // reaches only after finishing this fold. Safe via parity buffer.
    }

    __syncthreads();
    float* outb = out + (size_t)b * Tsz * 2;
    for (int i = tid; i < Tsz * 2; i += NT) outb[i] = out_s[i];
}

// ---------------------------------------------------------------------------
extern "C" void kernel_launch(void* const* d_in, const int* in_sizes, int n_in,
                              void* d_out, int out_size, void* d_ws, size_t ws_size,
                              hipStream_t stream) {
    const float* x     = (const float*)d_in[0];
    const float* W_ih  = (const float*)d_in[1];
    const float* W_hh  = (const float*)d_in[2];
    const float* fc_w  = (const float*)d_in[3];
    const float* fc_b  = (const float*)d_in[4];
    const float* enc_w = (const float*)d_in[5];
    float* outp = (float*)d_out;
    float* WB   = (float*)d_ws;            // 36*16384*4 = 2.25 MB

    retile_whh<<<NPAIR, 256, 0, stream>>>(W_hh, WB);
    cwrnn_kernel<<<Bsz, NT, 0, stream>>>(x, W_ih, fc_w, fc_b, enc_w, WB, outp);
}

// Round 7
// 1372.146 us; speedup vs baseline: 3.1767x; 3.1767x over previous
//
#include <hip/hip_runtime.h>
#include <hip/hip_fp16.h>
#include <math.h>

#define Bsz 128
#define Tsz 512
#define Hsz 1024
#define NM  8
#define MS  128
#define NT  512
#define NPAIR 36

// ws layout: [0, 64KB) WB0: fp32 block (0,0), j-fastest [row*128+j]
//            [64KB, +1.09MB) WBh: half blocks p=1..35, layout [j*128+row]

// ---------------------------------------------------------------------------
__global__ __launch_bounds__(256)
void retile_whh(const float* __restrict__ W, float* __restrict__ WB0,
                __half* __restrict__ WBh) {
    __shared__ float tile[MS][MS + 1];
    const int p = blockIdx.x;
    const int t = threadIdx.x;
    if (p == 0) {
        for (int idx = t; idx < MS * MS; idx += 256) {
            const int row = idx >> 7, j = idx & (MS - 1);
            WB0[idx] = W[row * Hsz + j];
        }
        return;
    }
    int c = 0;
    while ((c + 1) * (c + 2) / 2 <= p) ++c;
    const int r = p - c * (c + 1) / 2;
    for (int idx = t; idx < MS * MS; idx += 256) {
        const int row = idx >> 7, j = idx & (MS - 1);
        tile[row][j] = W[(size_t)(r * MS + row) * Hsz + c * MS + j];
    }
    __syncthreads();
    __half* wb = WBh + (size_t)(p - 1) * MS * MS;
    for (int idx = t; idx < MS * MS; idx += 256) {
        const int j = idx >> 7, row = idx & (MS - 1);
        wb[idx] = __float2half(tile[row][j]);
    }
}

__device__ __forceinline__ float fast_tanh(float x) {
    const float e = __expf(2.0f * x);
    return 1.0f - 2.0f * __builtin_amdgcn_rcpf(e + 1.0f);
}

union H4 { short4 s4; __half2 h2[2]; };

// ---------------------------------------------------------------------------
// Persistent per-batch-element Clockwork RNN. grid=128, block=512 (8 waves).
// R4 skeleton: 2 barriers/step, coalesced refresh (row4=(s&31)*4, jq=s>>5).
//
// Sp2[p][part][row]: 2 partials per (pair,row); part0 = jq{0,1} (wave A of a
//   slot), part1 = jq{2,3} (wave B), combined by intra-wave shfl_xor(32).
// Pair 0: fp32 register weights (32/thread), pairs 1,2: fp16 in LDS (64 KB),
// pairs >=3: fp16 streamed from L2 (coalesced short4-of-rows).
// ---------------------------------------------------------------------------
__global__ __launch_bounds__(NT)
void cwrnn_kernel(const float* __restrict__ x,      // [B, T+1, 2, 1]
                  const float* __restrict__ W_ih,   // [H, 2]
                  const float* __restrict__ fc_w,   // [2, H]
                  const float* __restrict__ fc_b,   // [2]
                  const float* __restrict__ enc_w,  // [H, 2]
                  const float* __restrict__ WB0,    // fp32 (0,0)
                  const __half* __restrict__ WBh,   // fp16 pairs 1..35
                  float* __restrict__ out)          // [B, T, 2]
{
    __shared__ __half wlds[2 * MS * MS];  // pairs 1,2: 64 KB
    __shared__ float  Sp2[NPAIR][2][MS];  // 36 KB
    __shared__ float  h_s[Hsz];
    __shared__ float2 x_s[Tsz + 1];
    __shared__ float2 wih_s[Hsz];
    __shared__ float2 fcw_s[Hsz];
    __shared__ float  out_s[Tsz * 2];
    __shared__ float2 ored[8];

    const int tid  = threadIdx.x;
    const int lane = tid & 63;
    const int wave = tid >> 6;
    const int b    = blockIdx.x;

    const float2* xb = (const float2*)(x + (size_t)b * (Tsz + 1) * 2);

    for (int i = tid; i < Tsz + 1; i += NT) x_s[i] = xb[i];
    for (int i = tid; i < Hsz; i += NT) wih_s[i] = ((const float2*)W_ih)[i];
    for (int i = tid; i < Hsz; i += NT)
        fcw_s[i] = make_float2(fc_w[i], fc_w[Hsz + i]);
    for (int i = tid; i < 2 * MS * MS / 4; i += NT)
        ((short4*)wlds)[i] = ((const short4*)WBh)[i];   // pairs 1,2 -> LDS
    const float fb0 = fc_b[0], fb1 = fc_b[1];

    // ---- (0,0) register cache: row00=tid>>2, jc=tid&3 (rotated chunks) ----
    const int row00 = tid >> 2;
    const int jc    = tid & 3;
    float4 w00[8];
    #pragma unroll
    for (int u = 0; u < 8; ++u) {
        const int uu = (u + 2 * jc) & 7;
        w00[u] = *(const float4*)(WB0 + row00 * MS + jc * 32 + uu * 4);
    }

    // ---- refresh_hi mapping (R4's coalesced one) ----
    const int slot = tid >> 7;            // pair slot 0..3
    const int s    = tid & 127;
    const int row4 = (s & 31) * 4;        // consecutive lanes -> consecutive rows
    const int jq   = s >> 5;              // 0,1 in wave A; 2,3 in wave B
    const int part = (tid >> 6) & 1;      // which Sp2 partial this wave owns
    const bool wr_gate = ((tid >> 5) & 1) == 0;

    // ---- h0 = x[:,0] @ enc_w.T ----
    {
        const float2 x0 = xb[0];
        for (int i = tid; i < Hsz; i += NT) {
            const float2 ew = ((const float2*)enc_w)[i];
            h_s[i] = x0.x * ew.x + x0.y * ew.y;
        }
    }
    __syncthreads();

    auto refresh00 = [&]() {
        float a = 0.f;
        #pragma unroll
        for (int u = 0; u < 8; ++u) {
            const int uu = (u + 2 * jc) & 7;
            const float4 hv = *(const float4*)(h_s + jc * 32 + uu * 4);
            a += w00[u].x * hv.x + w00[u].y * hv.y + w00[u].z * hv.z + w00[u].w * hv.w;
        }
        a += __shfl_xor(a, 1, 64);        // jc0+jc1 / jc2+jc3
        if (jc == 0)      Sp2[0][0][row00] = a;
        else if (jc == 2) Sp2[0][1][row00] = a;
    };

    auto pair_body = [&](const __half* __restrict__ wsrc, int c) -> float4 {
        const float* hc = h_s + c * MS;
        const __half* wp = wsrc + (size_t)(jq * 32) * MS + row4;
        float4 acc = {0.f, 0.f, 0.f, 0.f};
        #pragma unroll 8
        for (int jj = 0; jj < 32; ++jj) {
            const float hj = hc[jq * 32 + jj];
            H4 u; u.s4 = *(const short4*)(wp + (size_t)jj * MS);
            const float2 f01 = __half22float2(u.h2[0]);
            const float2 f23 = __half22float2(u.h2[1]);
            acc.x += f01.x * hj; acc.y += f01.y * hj;
            acc.z += f23.x * hj; acc.w += f23.y * hj;
        }
        return acc;
    };

    auto do_pair = [&](int p, int c) {
        float4 acc;
        if (p <= 2) acc = pair_body(wlds + (size_t)(p - 1) * MS * MS, c);
        else        acc = pair_body(WBh  + (size_t)(p - 1) * MS * MS, c);
        acc.x += __shfl_xor(acc.x, 32, 64); acc.y += __shfl_xor(acc.y, 32, 64);
        acc.z += __shfl_xor(acc.z, 32, 64); acc.w += __shfl_xor(acc.w, 32, 64);
        if (wr_gate) *(float4*)&Sp2[p][part][row4] = acc;
    };

    auto refresh_hi = [&](int P) {        // pairs 1..P-1, 4 concurrent
        for (int pb = 1; pb < P; pb += 4) {
            const int p = pb + slot;
            if (p < P) {
                const int c = (int)((sqrtf((float)(8 * p + 1)) - 1.0f) * 0.5f);
                do_pair(p, c);
            }
        }
    };

    refresh00();
    refresh_hi(NPAIR);
    __syncthreads();

    for (int t = 0; t < Tsz; ++t) {
        const int A = (t == 0) ? 7 : min(__ffs(t) - 1, 7);
        const int nrows = (A + 1) * MS;
        const float2 xt = x_s[t + 1];

        // ---- P1: candidate + h update ----
        for (int g = tid; g < nrows; g += NT) {
            const int r  = g >> 7;
            const int il = g & (MS - 1);
            const float2 wih2 = wih_s[g];
            float pre = xt.x * wih2.x + xt.y * wih2.y;
            for (int c = r; c < NM; ++c) {
                const int pidx = c * (c + 1) / 2 + r;
                pre += Sp2[pidx][0][il] + Sp2[pidx][1][il];
            }
            h_s[g] = fast_tanh(pre);
        }
        __syncthreads();                  // barrier 1

        // ---- P3: eager refresh (VMEM issued early) ----
        refresh00();
        refresh_hi((A + 1) * (A + 2) / 2);

        // ---- P2: out[t] = h @ fc_w.T + fc_b (wave partials) ----
        {
            const int j2 = tid * 2;
            const float2 h2 = *(const float2*)&h_s[j2];
            const float2 fw0 = fcw_s[j2 >> 1];     // (fc_w[0][j2..], fc_w[1][..])
            const float2 fw1 = fcw_s[(j2 >> 1) + 1];
            // fcw_s[i] = (fc_w0[i], fc_w1[i]); need elements j2, j2+1:
            float a0 = h2.x * fcw_s[j2].x + h2.y * fcw_s[j2 + 1].x;
            float a1 = h2.x * fcw_s[j2].y + h2.y * fcw_s[j2 + 1].y;
            (void)fw0; (void)fw1;
            #pragma unroll
            for (int o = 32; o > 0; o >>= 1) {
                a0 += __shfl_down(a0, o, 64);
                a1 += __shfl_down(a1, o, 64);
            }
            if (lane == 0) ored[wave] = make_float2(a0, a1);
        }
        __syncthreads();                  // barrier 2

        // ---- P4: stage step outputs (overlaps next P1's start) ----
        if (tid == 0) {
            float o0 = fb0, o1 = fb1;
            #pragma unroll
            for (int w = 0; w < 8; ++w) { o0 += ored[w].x; o1 += ored[w].y; }
            out_s[2 * t]     = o0;
            out_s[2 * t + 1] = o1;
        }
        // ored WAR: next write after next step's barrier 1. Safe.
    }

    __syncthreads();
    float* outb = out + (size_t)b * Tsz * 2;
    for (int i = tid; i < Tsz * 2; i += NT) outb[i] = out_s[i];
}

// ---------------------------------------------------------------------------
extern "C" void kernel_launch(void* const* d_in, const int* in_sizes, int n_in,
                              void* d_out, int out_size, void* d_ws, size_t ws_size,
                              hipStream_t stream) {
    const float* x     = (const float*)d_in[0];
    const float* W_ih  = (const float*)d_in[1];
    const float* W_hh  = (const float*)d_in[2];
    const float* fc_w  = (const float*)d_in[3];
    const float* fc_b  = (const float*)d_in[4];
    const float* enc_w = (const float*)d_in[5];
    float* outp = (float*)d_out;
    float*  WB0 = (float*)d_ws;                          // 64 KB
    __half* WBh = (__half*)((char*)d_ws + 65536);        // 35*16384*2 B

    retile_whh<<<NPAIR, 256, 0, stream>>>(W_hh, WB0, WBh);
    cwrnn_kernel<<<Bsz, NT, 0, stream>>>(x, W_ih, fc_w, fc_b, enc_w, WB0, WBh, outp);
}